// Round 14
// baseline (888.785 us; speedup 1.0000x reference)
//
#include <hip/hip_runtime.h>
#include <stdint.h>

// ---------------- problem constants ----------------
#define NHEAD  8
#define NLAYER 6
#define BATCH  2
#define LQ     12240
#define MTOK   (BATCH*LQ)     // 24480
#define MPAD   24576          // 192*128, so GEMM M-tiles need no bounds checks

typedef __attribute__((ext_vector_type(8))) short bf16x8;
typedef __attribute__((ext_vector_type(4))) float f32x4;
typedef __attribute__((ext_vector_type(4))) short s16x4;

__device__ __forceinline__ unsigned short f2bf(float f) {
  union { float f; uint32_t u; } v; v.f = f;
  uint32_t u = v.u;
  uint32_t r = (u + 0x7fffu + ((u >> 16) & 1u)) >> 16;  // RNE
  return (unsigned short)r;
}
__device__ __forceinline__ float bf2f(unsigned short s) {
  union { uint32_t u; float f; } v; v.u = ((uint32_t)s) << 16;
  return v.f;
}
__device__ __forceinline__ float hi_bf(uint32_t u) {
  union { uint32_t u; float f; } v; v.u = u & 0xffff0000u; return v.f;
}
__device__ __forceinline__ float lo_bf(uint32_t u) {
  union { uint32_t u; float f; } v; v.u = u << 16; return v.f;
}
__device__ __forceinline__ void gll16(const unsigned short* g, unsigned short* l) {
  __builtin_amdgcn_global_load_lds(
      (const __attribute__((address_space(1))) uint32_t*)g,
      (__attribute__((address_space(3))) uint32_t*)l, 16, 0, 0);
}

// ---------------- bf16 MFMA GEMM: C = A(MPAD x K) @ BT^T + bias ----------------
// BT is N x K row-major (pre-transposed weights). BM x 128 tile, BK=64,
// 4 waves in 2x2, wave sub-tile (BM/2)x64. global_load_lds width-16,
// XOR chunk swizzle (chunk ^= row&7) on the GLOBAL SOURCE side.
// EPI: 0 = fp32 store, 1 = bf16 store, 2 = relu + bf16 store.
template<int EPI, int BM>
__global__ __launch_bounds__(256)
void gemm_kernel(const unsigned short* __restrict__ A,
                 const unsigned short* __restrict__ BT,
                 const float* __restrict__ bias,
                 float* __restrict__ Cf,
                 unsigned short* __restrict__ Cb,
                 int K, int ldc)
{
  constexpr int MT = BM / 32;              // m-tiles per wave
  __shared__ unsigned short lA[BM*64];
  __shared__ unsigned short lB[128*64];
  const int tid  = threadIdx.x;
  const int lane = tid & 63;
  const int wm = ((tid >> 6) >> 1) * (BM/2);   // wave row offset in tile
  const int wn = ((tid >> 6) & 1) * 64;        // wave col offset in tile
  const size_t row0 = (size_t)blockIdx.x * BM;
  const size_t col0 = (size_t)blockIdx.y * 128;

  f32x4 acc[MT][4] = {};

  for (int kt = 0; kt < K; kt += 64) {
#pragma unroll
    for (int i = 0; i < MT; ++i) {             // A: BM*8/256 chunks/thread
      const int slot = i*256 + tid;
      const int r  = slot >> 3;
      const int cs = (slot & 7) ^ (r & 7);
      gll16(A + (row0 + r) * (size_t)K + kt + cs*8, &lA[slot*8]);
    }
#pragma unroll
    for (int i = 0; i < 4; ++i) {              // B: 1024/256 chunks/thread
      const int slot = i*256 + tid;
      const int r  = slot >> 3;
      const int cs = (slot & 7) ^ (r & 7);
      gll16(BT + (col0 + r) * (size_t)K + kt + cs*8, &lB[slot*8]);
    }
    __syncthreads();  // compiler drains vmcnt before s_barrier
#pragma unroll
    for (int kk = 0; kk < 2; ++kk) {
      bf16x8 af[MT], bfv[4];
#pragma unroll
      for (int m = 0; m < MT; ++m) {
        const int r  = wm + m*16 + (lane & 15);
        const int ch = (kk*4 + (lane >> 4)) ^ (r & 7);
        af[m] = *(const bf16x8*)(&lA[r*64 + ch*8]);
      }
#pragma unroll
      for (int n = 0; n < 4; ++n) {
        const int r  = wn + n*16 + (lane & 15);
        const int ch = (kk*4 + (lane >> 4)) ^ (r & 7);
        bfv[n] = *(const bf16x8*)(&lB[r*64 + ch*8]);
      }
#pragma unroll
      for (int m = 0; m < MT; ++m)
#pragma unroll
        for (int n = 0; n < 4; ++n)
          acc[m][n] = __builtin_amdgcn_mfma_f32_16x16x32_bf16(af[m], bfv[n], acc[m][n], 0, 0, 0);
    }
    __syncthreads();
  }

  // epilogue: C row = (lane>>4)*4 + i, col = lane&15 (verified m89 mapping)
  const int lq = lane >> 4;
  const int lr = lane & 15;
#pragma unroll
  for (int n = 0; n < 4; ++n) {
    const int col = (int)col0 + wn + n*16 + lr;
    const float bv = bias ? bias[col] : 0.f;
#pragma unroll
    for (int m = 0; m < MT; ++m) {
      const size_t rb = row0 + wm + m*16 + lq*4;
#pragma unroll
      for (int i = 0; i < 4; ++i) {
        float v = acc[m][n][i] + bv;
        if (EPI == 2) v = fmaxf(v, 0.f);
        if (EPI == 0) Cf[(rb + i) * (size_t)ldc + col] = v;
        else          Cb[(rb + i) * (size_t)ldc + col] = f2bf(v);
      }
    }
  }
}

// ------ fused qoa+val dispatch: blockIdx.y<3 -> q@[Woff|Watt] (bf16, ldc=384);
//        else x@Wval (bf16 row-major, ldc=256). Both BM=64, K=256.
__global__ __launch_bounds__(256)
void gemm_qv_kernel(const unsigned short* __restrict__ qbf,
                    const unsigned short* __restrict__ xbf,
                    const unsigned short* __restrict__ WoaT_l,
                    const unsigned short* __restrict__ WvalT_l,
                    const float* __restrict__ boa_l,
                    const float* __restrict__ bval_l,
                    unsigned short* __restrict__ Coab,
                    unsigned short* __restrict__ valbf)
{
  __shared__ unsigned short lA[64*64];
  __shared__ unsigned short lB[128*64];
  const bool isq = blockIdx.y < 3;
  const unsigned short* A  = isq ? qbf : xbf;
  const unsigned short* BT = isq ? WoaT_l : WvalT_l;
  const float* bias = isq ? boa_l : bval_l;
  const int colb = isq ? (int)blockIdx.y * 128 : ((int)blockIdx.y - 3) * 128;

  const int tid  = threadIdx.x;
  const int lane = tid & 63;
  const int wm = ((tid >> 6) >> 1) * 32;
  const int wn = ((tid >> 6) & 1) * 64;
  const size_t row0 = (size_t)blockIdx.x * 64;

  f32x4 acc[2][4] = {};

  for (int kt = 0; kt < 256; kt += 64) {
#pragma unroll
    for (int i = 0; i < 2; ++i) {
      const int slot = i*256 + tid;
      const int r  = slot >> 3;
      const int cs = (slot & 7) ^ (r & 7);
      gll16(A + (row0 + r) * 256 + kt + cs*8, &lA[slot*8]);
    }
#pragma unroll
    for (int i = 0; i < 4; ++i) {
      const int slot = i*256 + tid;
      const int r  = slot >> 3;
      const int cs = (slot & 7) ^ (r & 7);
      gll16(BT + (size_t)(colb + r) * 256 + kt + cs*8, &lB[slot*8]);
    }
    __syncthreads();
#pragma unroll
    for (int kk = 0; kk < 2; ++kk) {
      bf16x8 af[2], bfv[4];
#pragma unroll
      for (int m = 0; m < 2; ++m) {
        const int r  = wm + m*16 + (lane & 15);
        const int ch = (kk*4 + (lane >> 4)) ^ (r & 7);
        af[m] = *(const bf16x8*)(&lA[r*64 + ch*8]);
      }
#pragma unroll
      for (int n = 0; n < 4; ++n) {
        const int r  = wn + n*16 + (lane & 15);
        const int ch = (kk*4 + (lane >> 4)) ^ (r & 7);
        bfv[n] = *(const bf16x8*)(&lB[r*64 + ch*8]);
      }
#pragma unroll
      for (int m = 0; m < 2; ++m)
#pragma unroll
        for (int n = 0; n < 4; ++n)
          acc[m][n] = __builtin_amdgcn_mfma_f32_16x16x32_bf16(af[m], bfv[n], acc[m][n], 0, 0, 0);
    }
    __syncthreads();
  }

  const int lq = lane >> 4;
  const int lr = lane & 15;
#pragma unroll
  for (int n = 0; n < 4; ++n) {
    const int col = colb + wn + n*16 + lr;
    const float bv = bias[col];
#pragma unroll
    for (int m = 0; m < 2; ++m) {
      const size_t rb = row0 + wm + m*16 + lq*4;
#pragma unroll
      for (int i = 0; i < 4; ++i) {
        const float v = acc[m][n][i] + bv;
        if (isq) Coab[(rb + i) * 384 + col]  = f2bf(v);
        else     valbf[(rb + i) * 256 + col] = f2bf(v);
      }
    }
  }
}

// ------- fused GEMM + bias + residual(bf16) + LayerNorm -> bf16 outputs ------
// Tile 64x256, BK=64, 8 waves (512 thr) in 2 wave-rows x 4 wave-cols.
// MODE 0: LN1 -> xbf; MODE 1: LN2 mid -> xbf+qbf; MODE 2: LN2 last -> dout.
template<int MODE>
__global__ __launch_bounds__(512)
void gemm_ln_kernel(const unsigned short* __restrict__ A,
                    const unsigned short* __restrict__ BT,
                    const float* __restrict__ bias,
                    const unsigned short* __restrict__ xresbf,
                    const float* __restrict__ g,
                    const float* __restrict__ bn,
                    const unsigned short* __restrict__ posbf,
                    unsigned short* __restrict__ xbf,
                    unsigned short* __restrict__ qbf,
                    float* __restrict__ dout,
                    int K)
{
  __shared__ unsigned short lA[64*64];     // 8 KB
  __shared__ unsigned short lB[256*64];    // 32 KB
  __shared__ float rs1[4][64];
  __shared__ float rs2[4][64];
  const int tid  = threadIdx.x;
  const int lane = tid & 63;
  const int w    = tid >> 6;               // wave id 0..7
  const int wr   = w >> 2;                 // wave row (0..1) -> 32 rows each
  const int wc   = w & 3;                  // wave col (0..3) -> 64 cols each
  const size_t row0 = (size_t)blockIdx.x * 64;

  f32x4 acc[2][4] = {};

  for (int kt = 0; kt < K; kt += 64) {
    {
      const int slot = tid;
      const int r  = slot >> 3;
      const int cs = (slot & 7) ^ (r & 7);
      gll16(A + (row0 + r) * (size_t)K + kt + cs*8, &lA[slot*8]);
    }
#pragma unroll
    for (int i = 0; i < 4; ++i) {
      const int slot = i*512 + tid;
      const int r  = slot >> 3;
      const int cs = (slot & 7) ^ (r & 7);
      gll16(BT + (size_t)r * K + kt + cs*8, &lB[slot*8]);
    }
    __syncthreads();
#pragma unroll
    for (int kk = 0; kk < 2; ++kk) {
      bf16x8 af[2], bfv[4];
#pragma unroll
      for (int m = 0; m < 2; ++m) {
        const int r  = wr*32 + m*16 + (lane & 15);
        const int ch = (kk*4 + (lane >> 4)) ^ (r & 7);
        af[m] = *(const bf16x8*)(&lA[r*64 + ch*8]);
      }
#pragma unroll
      for (int n = 0; n < 4; ++n) {
        const int r  = wc*64 + n*16 + (lane & 15);
        const int ch = (kk*4 + (lane >> 4)) ^ (r & 7);
        bfv[n] = *(const bf16x8*)(&lB[r*64 + ch*8]);
      }
#pragma unroll
      for (int m = 0; m < 2; ++m)
#pragma unroll
        for (int n = 0; n < 4; ++n)
          acc[m][n] = __builtin_amdgcn_mfma_f32_16x16x32_bf16(af[m], bfv[n], acc[m][n], 0, 0, 0);
    }
    __syncthreads();
  }

  const int lq = lane >> 4;
  const int lr = lane & 15;
  float bcol[4], gcol[4], bncol[4];
#pragma unroll
  for (int n = 0; n < 4; ++n) {
    const int c = wc*64 + n*16 + lr;
    bcol[n]  = bias[c];
    gcol[n]  = g[c];
    bncol[n] = bn[c];
  }
#pragma unroll
  for (int m = 0; m < 2; ++m)
#pragma unroll
    for (int i = 0; i < 4; ++i) {
      const size_t row = row0 + wr*32 + m*16 + lq*4 + i;
#pragma unroll
      for (int n = 0; n < 4; ++n)
        acc[m][n][i] += bcol[n] + bf2f(xresbf[row*256 + wc*64 + n*16 + lr]);
    }
#pragma unroll
  for (int m = 0; m < 2; ++m)
#pragma unroll
    for (int i = 0; i < 4; ++i) {
      float t1 = acc[m][0][i] + acc[m][1][i] + acc[m][2][i] + acc[m][3][i];
      float t2 = acc[m][0][i]*acc[m][0][i] + acc[m][1][i]*acc[m][1][i]
               + acc[m][2][i]*acc[m][2][i] + acc[m][3][i]*acc[m][3][i];
#pragma unroll
      for (int o = 1; o < 16; o <<= 1) {
        t1 += __shfl_xor(t1, o, 64);
        t2 += __shfl_xor(t2, o, 64);
      }
      if (lr == 0) {
        rs1[wc][wr*32 + m*16 + lq*4 + i] = t1;
        rs2[wc][wr*32 + m*16 + lq*4 + i] = t2;
      }
    }
  __syncthreads();
#pragma unroll
  for (int m = 0; m < 2; ++m)
#pragma unroll
    for (int i = 0; i < 4; ++i) {
      const int r = wr*32 + m*16 + lq*4 + i;
      const float s1 = rs1[0][r] + rs1[1][r] + rs1[2][r] + rs1[3][r];
      const float s2 = rs2[0][r] + rs2[1][r] + rs2[2][r] + rs2[3][r];
      const float mu  = s1 * (1.f/256.f);
      const float var = s2 * (1.f/256.f) - mu*mu;
      const float rstd = rsqrtf(var + 1e-5f);
      const size_t row = row0 + r;
#pragma unroll
      for (int n = 0; n < 4; ++n) {
        const int c = wc*64 + n*16 + lr;
        const float nv = (acc[m][n][i] - mu) * rstd * gcol[n] + bncol[n];
        const size_t idx = row*256 + c;
        if (MODE == 2) {
          if (row < MTOK) dout[idx] = nv;
        } else {
          xbf[idx] = f2bf(nv);
          if (MODE == 1) qbf[idx] = f2bf(nv + bf2f(posbf[idx]));
        }
      }
    }
}

// ---------------- input pack: (B,256,HW) -> xbf (bf16) / posbf (bf16) -------
__global__ void pack_kernel(const float* __restrict__ s0, const float* __restrict__ s1,
                            const float* __restrict__ s2, const float* __restrict__ s3,
                            const float* __restrict__ p0, const float* __restrict__ p1,
                            const float* __restrict__ p2, const float* __restrict__ p3,
                            const float* __restrict__ lev,
                            unsigned short* __restrict__ xo, unsigned short* __restrict__ po)
{
  const int bt = blockIdx.x;
  int lvl, st;
  if      (bt < 288) { lvl = 0; st = bt; }
  else if (bt < 360) { lvl = 1; st = bt - 288; }
  else if (bt < 378) { lvl = 2; st = bt - 360; }
  else               { lvl = 3; st = bt - 378; }
  const int HWs[4] = {9216, 2304, 576, 144};
  const int LSs[4] = {0, 9216, 11520, 12096};
  const int hw = HWs[lvl], ls = LSs[lvl];
  const int b = blockIdx.z & 1, isp = blockIdx.z >> 1;
  const float* ins[8] = {s0, s1, s2, s3, p0, p1, p2, p3};
  const float* in = ins[isp*4 + lvl];
  const int sbase = st*32, d0 = blockIdx.y*32;
  __shared__ float tile[32][33];
  const int tx = threadIdx.x, ty = threadIdx.y;
#pragma unroll
  for (int j = 0; j < 4; ++j) {
    int ss = sbase + tx;
    int dd = d0 + ty + j*8;
    tile[ty + j*8][tx] = (ss < hw) ? in[((size_t)b*256 + dd)*hw + ss] : 0.f;
  }
  __syncthreads();
  const float addv = isp ? lev[lvl*256 + d0 + tx] : 0.f;
  unsigned short* outp = isp ? po : xo;
#pragma unroll
  for (int j = 0; j < 4; ++j) {
    int ss = sbase + ty + j*8;
    if (ss < hw)
      outp[(size_t)(b*LQ + ls + ss)*256 + d0 + tx] = f2bf(tile[tx][ty + j*8] + addv);
  }
}

// ---------------- weight transpose+convert: W(K,N) f32 -> WT(N,K) bf16 -------
__global__ void wtrans_kernel(const float* __restrict__ Woff, const float* __restrict__ Watt,
                              const float* __restrict__ Wval, const float* __restrict__ Wout,
                              const float* __restrict__ Wf1,  const float* __restrict__ Wf2,
                              unsigned short* __restrict__ WoaT, unsigned short* __restrict__ WvalT,
                              unsigned short* __restrict__ WoutT, unsigned short* __restrict__ Wf1T,
                              unsigned short* __restrict__ Wf2T)
{
  const int li = blockIdx.z;
  const int bt = blockIdx.x;
  const float* in; unsigned short* out; int Kd, Nd, tn, tIdx;
  if      (bt < 64)  { in = Woff + (size_t)li*65536;  out = WoaT  + (size_t)li*98304;         Kd=256;  Nd=256;  tn=8;  tIdx=bt; }
  else if (bt < 96)  { in = Watt + (size_t)li*32768;  out = WoaT  + (size_t)li*98304 + 65536; Kd=256;  Nd=128;  tn=4;  tIdx=bt-64; }
  else if (bt < 160) { in = Wval + (size_t)li*65536;  out = WvalT + (size_t)li*65536;         Kd=256;  Nd=256;  tn=8;  tIdx=bt-96; }
  else if (bt < 224) { in = Wout + (size_t)li*65536;  out = WoutT + (size_t)li*65536;         Kd=256;  Nd=256;  tn=8;  tIdx=bt-160; }
  else if (bt < 480) { in = Wf1  + (size_t)li*262144; out = Wf1T  + (size_t)li*262144;        Kd=256;  Nd=1024; tn=32; tIdx=bt-224; }
  else               { in = Wf2  + (size_t)li*262144; out = Wf2T  + (size_t)li*262144;        Kd=1024; Nd=256;  tn=8;  tIdx=bt-480; }
  const int kt = tIdx / tn, nt = tIdx - kt*tn;
  const int k0 = kt*32, n0 = nt*32;
  __shared__ float tile[32][33];
  const int tx = threadIdx.x, ty = threadIdx.y;
#pragma unroll
  for (int j = 0; j < 4; ++j)
    tile[ty + j*8][tx] = in[(size_t)(k0 + ty + j*8) * Nd + n0 + tx];
  __syncthreads();
#pragma unroll
  for (int j = 0; j < 4; ++j)
    out[(size_t)(n0 + ty + j*8) * Kd + k0 + tx] = f2bf(tile[tx][ty + j*8]);
}

__global__ void bias_concat_kernel(const float* __restrict__ boff, const float* __restrict__ batt,
                                   float* __restrict__ boa)
{
  const int li = blockIdx.x, i = threadIdx.x;  // 384 threads
  boa[li*384 + i] = (i < 256) ? boff[li*256 + i] : batt[li*128 + (i - 256)];
}

// -------- prep (each launch): qbf = bf16(x+pos); zero pad rows of xbf/qbf ----
__global__ void prep_kernel(unsigned short* __restrict__ xbf,
                            const unsigned short* __restrict__ posbf,
                            unsigned short* __restrict__ qbf)
{
  const int idx = blockIdx.x * 256 + threadIdx.x;   // s16x4 units, MPAD*64 total
  const int row = idx >> 6;
  if (row < MTOK) {
    const s16x4 xv = *(const s16x4*)(xbf + (size_t)idx*4);
    const s16x4 pv = *(const s16x4*)(posbf + (size_t)idx*4);
    s16x4 qb;
#pragma unroll
    for (int j = 0; j < 4; ++j)
      qb[j] = (short)f2bf(bf2f((unsigned short)xv[j]) + bf2f((unsigned short)pv[j]));
    *(s16x4*)(qbf + (size_t)idx*4) = qb;
  } else {
    const s16x4 z = {};
    *(s16x4*)(xbf + (size_t)idx*4) = z;
    *(s16x4*)(qbf + (size_t)idx*4) = z;
  }
}

// ---------------- fused softmax + point-prep + deformable gather -------------
// Coab is bf16 (MPAD x 384): offsets + logits. val is BF16 row-major:
// one 8-lane group-corner = 64 B = a single L1 line (halves TA transactions
// vs fp32). Block = 256 threads = 32 groups of 8 lanes; lane = 4 channels.
// XCD-chunked blockIdx swizzle: grid 6144 = 8*768, bijective.
__global__ __launch_bounds__(256)
void sample_kernel(const unsigned short* __restrict__ Coab,
                   const unsigned short* __restrict__ valbf,
                   unsigned short* __restrict__ outbf)
{
  __shared__ int4  pdo[32][17];
  __shared__ f32x4 pdw[32][17];
  const int tid = threadIdx.x;
  const int gi  = tid >> 3;                // group within block, 0..31
  const int bid = blockIdx.x;
  const int swz = (bid & 7) * ((MPAD/4) >> 3) + (bid >> 3);   // XCD-chunked
  const int g   = swz * 32 + gi;           // global (t*8 + h)
  const int t   = g >> 3, h = g & 7;
  const int b   = (t >= LQ) ? 1 : 0;

  // ---- phase 1: two descriptors per thread ----
  {
    const int i0 = tid & 7;                // first point index; second is i0+8
    int4  ov0 = {0,0,0,0}, ov1 = {0,0,0,0};
    f32x4 wv0 = {0,0,0,0}, wv1 = {0,0,0,0};
    if (t < MTOK) {
      const int q = t - b * LQ;
      float refx, refy;
      if      (q < 9216)  { const int r = q;         const int rw = r/96; refx = (r - rw*96 + 0.5f)*(1.f/96.f); refy = (rw + 0.5f)*(1.f/96.f); }
      else if (q < 11520) { const int r = q - 9216;  const int rw = r/48; refx = (r - rw*48 + 0.5f)*(1.f/48.f); refy = (rw + 0.5f)*(1.f/48.f); }
      else if (q < 12096) { const int r = q - 11520; const int rw = r/24; refx = (r - rw*24 + 0.5f)*(1.f/24.f); refy = (rw + 0.5f)*(1.f/24.f); }
      else                { const int r = q - 12096; const int rw = r/12; refx = (r - rw*12 + 0.5f)*(1.f/12.f); refy = (rw + 0.5f)*(1.f/12.f); }
      const size_t crow = (size_t)t * 384;
      const float l0 = bf2f(Coab[crow + 256 + h*16 + i0]);
      const float l1 = bf2f(Coab[crow + 256 + h*16 + i0 + 8]);
      float mx = fmaxf(l0, l1);
#pragma unroll
      for (int m = 1; m < 8; m <<= 1) mx = fmaxf(mx, __shfl_xor(mx, m, 64));
      const float e0 = __expf(l0 - mx), e1 = __expf(l1 - mx);
      float sum = e0 + e1;
#pragma unroll
      for (int m = 1; m < 8; m <<= 1) sum += __shfl_xor(sum, m, 64);
      const float inv = 1.f / sum;

      auto mkpd = [&](int i, float aw, int4& ov, f32x4& wv) {
        const int l    = i >> 2;
        const int wl   = (l == 0) ? 96 : (l == 1) ? 48 : (l == 2) ? 24 : 12;
        const int base = (l == 0) ? 0  : (l == 1) ? 9216 : (l == 2) ? 11520 : 12096;
        const float ox = bf2f(Coab[crow + h*32 + 2*i]);
        const float oy = bf2f(Coab[crow + h*32 + 2*i + 1]);
        const float fw = (float)wl;
        const float xx = refx*fw + ox - 0.5f;
        const float yy = refy*fw + oy - 0.5f;
        const float xf = floorf(xx), yf = floorf(yy);
        const int x0 = (int)xf, y0 = (int)yf;
        const float lx = xx - xf, ly = yy - yf;
        const bool vx0 = (x0   >= 0) & (x0   < wl);
        const bool vx1 = (x0+1 >= 0) & (x0+1 < wl);
        const bool vy0 = (y0   >= 0) & (y0   < wl);
        const bool vy1 = (y0+1 >= 0) & (y0+1 < wl);
        const int cx0 = min(max(x0,   0), wl-1);
        const int cx1 = min(max(x0+1, 0), wl-1);
        const int cy0 = min(max(y0,   0), wl-1);
        const int cy1 = min(max(y0+1, 0), wl-1);
        ov.x = (base + cy0*wl + cx0) * 512;    // byte offsets (256 ch * 2 B)
        ov.y = (base + cy0*wl + cx1) * 512;
        ov.z = (base + cy1*wl + cx0) * 512;
        ov.w = (base + cy1*wl + cx1) * 512;
        wv[0] = (vx0 & vy0) ? (1.f-lx)*(1.f-ly)*aw : 0.f;
        wv[1] = (vx1 & vy0) ? lx*(1.f-ly)*aw       : 0.f;
        wv[2] = (vx0 & vy1) ? (1.f-lx)*ly*aw       : 0.f;
        wv[3] = (vx1 & vy1) ? lx*ly*aw             : 0.f;
      };
      mkpd(i0,     e0 * inv, ov0, wv0);
      mkpd(i0 + 8, e1 * inv, ov1, wv1);
    }
    pdo[gi][i0]     = ov0;  pdw[gi][i0]     = wv0;
    pdo[gi][i0 + 8] = ov1;  pdw[gi][i0 + 8] = wv1;
  }
  __syncthreads();

  // ---- phase 2: gather (bf16 uint2 loads + bit-op unpack) ----
  const int lane8 = tid & 7;
  const char* vb = (const char*)(valbf + (size_t)b*LQ*256 + h*32 + lane8*4);
  const int4*  po8 = pdo[gi];
  const f32x4* pw8 = pdw[gi];
  f32x4 a0 = {}, a1 = {}, a2 = {}, a3 = {};
#pragma unroll
  for (int p = 0; p < 16; ++p) {
    const int4  o = po8[p];
    const f32x4 w = pw8[p];
    const uint2 c0 = *(const uint2*)(vb + o.x);
    const uint2 c1 = *(const uint2*)(vb + o.y);
    const uint2 c2 = *(const uint2*)(vb + o.z);
    const uint2 c3 = *(const uint2*)(vb + o.w);
    a0[0] += w[0]*lo_bf(c0.x); a0[1] += w[0]*hi_bf(c0.x); a0[2] += w[0]*lo_bf(c0.y); a0[3] += w[0]*hi_bf(c0.y);
    a1[0] += w[1]*lo_bf(c1.x); a1[1] += w[1]*hi_bf(c1.x); a1[2] += w[1]*lo_bf(c1.y); a1[3] += w[1]*hi_bf(c1.y);
    a2[0] += w[2]*lo_bf(c2.x); a2[1] += w[2]*hi_bf(c2.x); a2[2] += w[2]*lo_bf(c2.y); a2[3] += w[2]*hi_bf(c2.y);
    a3[0] += w[3]*lo_bf(c3.x); a3[1] += w[3]*hi_bf(c3.x); a3[2] += w[3]*lo_bf(c3.y); a3[3] += w[3]*hi_bf(c3.y);
  }
  s16x4 ob;
#pragma unroll
  for (int j = 0; j < 4; ++j) ob[j] = (short)f2bf((a0[j] + a1[j]) + (a2[j] + a3[j]));
  *(s16x4*)(outbf + (size_t)t*256 + h*32 + lane8*4) = ob;
}

// ---------------- launch ----------------
extern "C" void kernel_launch(void* const* d_in, const int* in_sizes, int n_in,
                              void* d_out, int out_size, void* d_ws, size_t ws_size,
                              hipStream_t stream)
{
  const float* src0 = (const float*)d_in[0];
  const float* pos0 = (const float*)d_in[1];
  const float* src1 = (const float*)d_in[2];
  const float* pos1 = (const float*)d_in[3];
  const float* src2 = (const float*)d_in[4];
  const float* pos2 = (const float*)d_in[5];
  const float* src3 = (const float*)d_in[6];
  const float* pos3 = (const float*)d_in[7];
  const float* lev  = (const float*)d_in[8];
  const float* W_off= (const float*)d_in[9];
  const float* b_off= (const float*)d_in[10];
  const float* W_att= (const float*)d_in[11];
  const float* b_att= (const float*)d_in[12];
  const float* W_val= (const float*)d_in[13];
  const float* b_val= (const float*)d_in[14];
  const float* W_out= (const float*)d_in[15];
  const float* b_out= (const float*)d_in[16];
  const float* ln1g = (const float*)d_in[17];
  const float* ln1b = (const float*)d_in[18];
  const float* W_f1 = (const float*)d_in[19];
  const float* b_f1 = (const float*)d_in[20];
  const float* W_f2 = (const float*)d_in[21];
  const float* b_f2 = (const float*)d_in[22];
  const float* ln2g = (const float*)d_in[23];
  const float* ln2b = (const float*)d_in[24];

  char* wp = (char*)d_ws;
  auto take = [&](size_t bytes) { char* p = wp; wp += (bytes + 255) & ~(size_t)255; return p; };
  unsigned short* valbf  = (unsigned short*)take((size_t)MPAD*256*2);
  unsigned short* posbf  = (unsigned short*)take((size_t)MPAD*256*2);
  unsigned short* Coab   = (unsigned short*)take((size_t)MPAD*384*2);
  unsigned short* xbf    = (unsigned short*)take((size_t)MPAD*256*2);
  unsigned short* qbf    = (unsigned short*)take((size_t)MPAD*256*2);
  unsigned short* sampbf = (unsigned short*)take((size_t)MPAD*256*2);
  unsigned short* h1bf   = (unsigned short*)take((size_t)MPAD*1024*2);
  unsigned short* WoaT   = (unsigned short*)take((size_t)NLAYER*384*256*2);
  unsigned short* WvalT  = (unsigned short*)take((size_t)NLAYER*256*256*2);
  unsigned short* WoutT  = (unsigned short*)take((size_t)NLAYER*256*256*2);
  unsigned short* Wf1T   = (unsigned short*)take((size_t)NLAYER*1024*256*2);
  unsigned short* Wf2T   = (unsigned short*)take((size_t)NLAYER*256*1024*2);
  float* boa  = (float*)take((size_t)NLAYER*384*4);

  dim3 tb(32, 8);
  pack_kernel<<<dim3(383, 8, 4), tb, 0, stream>>>(src0, src1, src2, src3,
                                                  pos0, pos1, pos2, pos3, lev, xbf, posbf);
  wtrans_kernel<<<dim3(736, 1, 6), tb, 0, stream>>>(W_off, W_att, W_val, W_out, W_f1, W_f2,
                                                    WoaT, WvalT, WoutT, Wf1T, Wf2T);
  bias_concat_kernel<<<NLAYER, 384, 0, stream>>>(b_off, b_att, boa);
  prep_kernel<<<MPAD/4, 256, 0, stream>>>(xbf, posbf, qbf);   // qbf + pad zeroing

  for (int li = 0; li < NLAYER; ++li) {
    // fused: q @ [W_off|W_attn] -> Coab (bf16) AND x @ W_val -> valbf (bf16)
    gemm_qv_kernel<<<dim3(MPAD/64, 5), 256, 0, stream>>>(qbf, xbf,
        WoaT + (size_t)li*98304, WvalT + (size_t)li*65536,
        boa + li*384, b_val + li*256, Coab, valbf);
    // fused softmax + point prep + gather (XCD-swizzled, bf16 val)
    sample_kernel<<<MPAD/4, 256, 0, stream>>>(Coab, valbf, sampbf);
    // sampled @ W_out + b_out + residual -> LN1 -> xbf   (fused, bf16 residual)
    gemm_ln_kernel<0><<<MPAD/64, 512, 0, stream>>>(sampbf, WoutT + (size_t)li*65536,
        b_out + li*256, xbf, ln1g + li*256, ln1b + li*256, nullptr,
        xbf, nullptr, nullptr, 256);
    // relu(x @ W_ffn1) -> h1bf (bf16)
    gemm_kernel<2,128><<<dim3(MPAD/128, 8), 256, 0, stream>>>(xbf, Wf1T + (size_t)li*262144,
        b_f1 + li*1024, nullptr, h1bf, 256, 1024);
    // h1 @ W_ffn2 + b + residual -> LN2 -> xbf, qbf (or d_out on last layer)
    if (li < NLAYER-1)
      gemm_ln_kernel<1><<<MPAD/64, 512, 0, stream>>>(h1bf, Wf2T + (size_t)li*262144,
          b_f2 + li*256, xbf, ln2g + li*256, ln2b + li*256, posbf,
          xbf, qbf, nullptr, 1024);
    else
      gemm_ln_kernel<2><<<MPAD/64, 512, 0, stream>>>(h1bf, Wf2T + (size_t)li*262144,
          b_f2 + li*256, xbf, ln2g + li*256, ln2b + li*256, nullptr,
          nullptr, nullptr, (float*)d_out, 1024);
  }
}